// Round 6
// baseline (576.697 us; speedup 1.0000x reference)
//
#include <hip/hip_runtime.h>

typedef short bf16x8 __attribute__((ext_vector_type(8)));
typedef short bf16x4 __attribute__((ext_vector_type(4)));
typedef float f32x4 __attribute__((ext_vector_type(4)));

#define MFMA16(a, b, c) __builtin_amdgcn_mfma_f32_16x16x32_bf16(a, b, c, 0, 0, 0)

__device__ __forceinline__ short f2bf(float f) {
  unsigned u = __builtin_bit_cast(unsigned, f);
  u += 0x7fffu + ((u >> 16) & 1u);   // round-to-nearest-even
  return (short)(u >> 16);
}
__device__ __forceinline__ float bf2f(short s) {
  return __builtin_bit_cast(float, ((unsigned)(unsigned short)s) << 16);
}

// Problem sizes (fixed)
// B=4, N=2048, D=512, H=8, DH=64, M = B*N = 8192, 3*H*DH = 1536
#define L2E 1.44269504088896f

// ---------------- prep kernels ----------------

__global__ __launch_bounds__(256) void cvt_bf16(const float* __restrict__ in,
                                                short* __restrict__ out) {
  size_t i = ((size_t)blockIdx.x * 256 + threadIdx.x) * 8;
  const float4* p = (const float4*)(in + i);
  float4 a = p[0], b = p[1];
  bf16x8 v;
  v[0] = f2bf(a.x); v[1] = f2bf(a.y); v[2] = f2bf(a.z); v[3] = f2bf(a.w);
  v[4] = f2bf(b.x); v[5] = f2bf(b.y); v[6] = f2bf(b.z); v[7] = f2bf(b.w);
  *(bf16x8*)(out + i) = v;
}

// bias fp32 -> bf16 with L2E folded, layout unchanged [h][q][key].
// Pure streaming (float4 in, bf16x8 out) — replaces the old bias_pack whose
// 16x scalar-fp32 loads ran at 1/4 load throughput.
__global__ __launch_bounds__(256) void bias_cvt(const float* __restrict__ in,
                                                short* __restrict__ out) {
  size_t i = ((size_t)blockIdx.x * 256 + threadIdx.x) * 8;
  const float4* p = (const float4*)(in + i);
  float4 a = p[0], b = p[1];
  bf16x8 v;
  v[0] = f2bf(a.x * L2E); v[1] = f2bf(a.y * L2E);
  v[2] = f2bf(a.z * L2E); v[3] = f2bf(a.w * L2E);
  v[4] = f2bf(b.x * L2E); v[5] = f2bf(b.y * L2E);
  v[6] = f2bf(b.z * L2E); v[7] = f2bf(b.w * L2E);
  *(bf16x8*)(out + i) = v;
}

// in: fp32 [K][N] -> out: bf16 [N][K]
__global__ __launch_bounds__(256) void transpose_cvt(const float* __restrict__ in,
                                                     short* __restrict__ out,
                                                     int K, int N) {
  __shared__ short Ts[64][72];
  const int t = threadIdx.x;
  const int k0 = blockIdx.y * 64, n1 = blockIdx.x * 64;
  const int kk = t >> 2, nq = (t & 3) * 16;
  const float* src = in + (size_t)(k0 + kk) * N + n1 + nq;
#pragma unroll
  for (int i = 0; i < 16; ++i) Ts[nq + i][kk] = f2bf(src[i]);
  __syncthreads();
  const int n = t >> 2, kq = (t & 3) * 16;
  short* dst = out + (size_t)(n1 + n) * K + k0 + kq;
  *(bf16x8*)dst = *(const bf16x8*)&Ts[n][kq];
  *(bf16x8*)(dst + 8) = *(const bf16x8*)&Ts[n][kq + 8];
}

// ---------------- shared GEMM mainloop: C[128x128] tile, K=512 ----------------
// A: bf16 [M][512] row-major; BT: bf16 [Ncols][512] (i.e. B transposed)

__device__ __forceinline__ void gemm128_mainloop(const short* __restrict__ A,
                                                 const short* __restrict__ BT,
                                                 int m0, int n0,
                                                 short (*As)[40], short (*Bs)[40],
                                                 f32x4 acc[4][4]) {
  const int t = threadIdx.x;
  const int w = t >> 6, lane = t & 63, l15 = lane & 15, quad = lane >> 4;
  const int wm = (w & 1) * 64, wn = (w >> 1) * 64;
  const int srow = t >> 1, skg = (t & 1) * 16;
  const short* aptr = A + (size_t)(m0 + srow) * 512 + skg;
  const short* bptr = BT + (size_t)(n0 + srow) * 512 + skg;
  for (int k0 = 0; k0 < 512; k0 += 32) {
    __syncthreads();
    *(bf16x8*)&As[srow][skg]     = *(const bf16x8*)(aptr + k0);
    *(bf16x8*)&As[srow][skg + 8] = *(const bf16x8*)(aptr + k0 + 8);
    *(bf16x8*)&Bs[srow][skg]     = *(const bf16x8*)(bptr + k0);
    *(bf16x8*)&Bs[srow][skg + 8] = *(const bf16x8*)(bptr + k0 + 8);
    __syncthreads();
    bf16x8 af[4], bfr[4];
#pragma unroll
    for (int i = 0; i < 4; ++i) af[i] = *(const bf16x8*)&As[wm + i * 16 + l15][quad * 8];
#pragma unroll
    for (int j = 0; j < 4; ++j) bfr[j] = *(const bf16x8*)&Bs[wn + j * 16 + l15][quad * 8];
#pragma unroll
    for (int i = 0; i < 4; ++i)
#pragma unroll
      for (int j = 0; j < 4; ++j)
        acc[i][j] = MFMA16(af[i], bfr[j], acc[i][j]);
  }
}

// ---------------- K1: QKV projection ----------------

__global__ __launch_bounds__(256) void gemm_qkv(const short* __restrict__ A,
                                                const short* __restrict__ BT,
                                                short* __restrict__ q_ws,
                                                short* __restrict__ k_ws,
                                                short* __restrict__ v_t) {
  __shared__ short As[128][40];
  __shared__ short Bs[128][40];
  __shared__ short Ts[64][136];
  const int t = threadIdx.x;
  const int w = t >> 6, lane = t & 63, l15 = lane & 15, quad = lane >> 4;
  const int wm = (w & 1) * 64, wn = (w >> 1) * 64;
  const int m0 = blockIdx.y * 128, n0 = blockIdx.x * 128;
  f32x4 acc[4][4];
#pragma unroll
  for (int i = 0; i < 4; ++i)
#pragma unroll
    for (int j = 0; j < 4; ++j) acc[i][j] = (f32x4){0.f, 0.f, 0.f, 0.f};

  gemm128_mainloop(A, BT, m0, n0, As, Bs, acc);

  const int which = n0 >> 9;            // 0=q 1=k 2=v
  const int b = m0 >> 11, seq0 = m0 & 2047;
  if (which < 2) {
    short* dst = (which == 0) ? q_ws : k_ws;
    const float scale = (which == 0) ? (0.125f * L2E) : 1.0f;
#pragma unroll
    for (int i = 0; i < 4; ++i)
#pragma unroll
      for (int j = 0; j < 4; ++j)
#pragma unroll
        for (int r = 0; r < 4; ++r) {
          int m_loc = wm + i * 16 + quad * 4 + r;
          int col = n0 + wn + j * 16 + l15;
          int h = (col >> 6) & 7, d = col & 63;
          dst[((size_t)(b * 8 + h) * 2048 + seq0 + m_loc) * 64 + d] =
              f2bf(acc[i][j][r] * scale);
        }
  } else {
    for (int half = 0; half < 2; ++half) {
      __syncthreads();
      if ((w >> 1) == half) {
#pragma unroll
        for (int i = 0; i < 4; ++i)
#pragma unroll
          for (int j = 0; j < 4; ++j)
#pragma unroll
            for (int r = 0; r < 4; ++r)
              Ts[j * 16 + l15][wm + i * 16 + quad * 4 + r] = f2bf(acc[i][j][r]);
      }
      __syncthreads();
      const int hd = ((n0 + half * 64) >> 6) & 7;
      const int dp = t >> 2, sq = (t & 3) * 32;
      short* dstp = v_t + ((size_t)(b * 8 + hd) * 64 + dp) * 2048 + seq0 + sq;
#pragma unroll
      for (int u = 0; u < 4; ++u)
        *(bf16x8*)(dstp + u * 8) = *(const bf16x8*)&Ts[dp][sq + u * 8];
    }
  }
}

// ---------------- K2: fused flash attention, key-split across blocks ----------
// 256 threads = 4 waves = 4 q-strips of 16 queries; block does 1024 keys.
// S^T trick: MFMA16(aK, aQ) gives C[row=key=quad*4+r][col=q=l15], so each
// lane owns 4 CONSECUTIVE keys at its own q: P-write is 4x ds_write_b64
// (was 16x ds_write_b16), bias is 4x bf16x4 loads from the untransposed
// [h][q][key] bf16 bias, and lsum is a per-lane scalar (2-step shuffle at
// the very end). Bias is software-prefetched one chunk ahead.
// NO min-waves launch bound: (512,N) variants forced accumulator spill
// (WRITE_SIZE 8MB -> 268..725MB). Occupancy is register-granule-capped at
// ~16 waves/CU regardless of grid — so we shorten the serial chain instead.

__global__ __launch_bounds__(256) void attn_kernel(const short* __restrict__ q_ws,
                                                   const short* __restrict__ k_ws,
                                                   const short* __restrict__ v_t,
                                                   const short* __restrict__ biasT,
                                                   float* __restrict__ Opart,
                                                   float* __restrict__ lpart) {
  __shared__ __align__(16) short Plds[2][4][16][72];  // [parity][wave][q][key]
  const int t = threadIdx.x;
  const int w = t >> 6, lane = t & 63, l15 = lane & 15, quad = lane >> 4;
  const int bid = blockIdx.x;
  const int b = bid & 3;                 // batch fastest: bias L3 reuse
  const int half = (bid >> 2) & 1;
  const int h = (bid >> 3) & 7;
  const int qb = bid >> 6;               // 0..31
  const int bh = b * 8 + h;
  const int q0 = qb * 64 + w * 16;

  const size_t qbase = ((size_t)bh * 2048 + q0 + l15) * 64 + quad * 8;
  bf16x8 aQ0 = *(const bf16x8*)(q_ws + qbase);
  bf16x8 aQ1 = *(const bf16x8*)(q_ws + qbase + 32);

  f32x4 O[4];
#pragma unroll
  for (int i = 0; i < 4; ++i) O[i] = (f32x4){0.f, 0.f, 0.f, 0.f};
  float lacc = 0.f;                      // per-lane, q = l15

  // bias row for this lane's q; lane needs keys j0 + nt*16 + quad*4 .. +3
  const short* brow = biasT + ((size_t)h * 2048 + q0 + l15) * 2048 + quad * 4;
  const short* kb = k_ws + (size_t)bh * 2048 * 64 + quad * 8;
  const short* vb = v_t + (size_t)bh * 64 * 2048 + quad * 8;

  const int jlo = half * 1024, jhi = jlo + 1024;

  bf16x4 bnx[4];
#pragma unroll
  for (int nt = 0; nt < 4; ++nt) bnx[nt] = *(const bf16x4*)(brow + jlo + nt * 16);

#pragma unroll 2
  for (int j0 = jlo; j0 < jhi; j0 += 64) {
    const int buf = (j0 >> 6) & 1;
    bf16x4 bv[4];
#pragma unroll
    for (int nt = 0; nt < 4; ++nt) bv[nt] = bnx[nt];
    const int jn = (j0 + 64 < jhi) ? (j0 + 64) : jlo;   // prefetch next chunk
#pragma unroll
    for (int nt = 0; nt < 4; ++nt) bnx[nt] = *(const bf16x4*)(brow + jn + nt * 16);

    f32x4 S[4];
#pragma unroll
    for (int nt = 0; nt < 4; ++nt) {
      const short* kp = kb + (size_t)(j0 + nt * 16 + l15) * 64;
      bf16x8 aK0 = *(const bf16x8*)kp;
      bf16x8 aK1 = *(const bf16x8*)(kp + 32);
      f32x4 s;
#pragma unroll
      for (int r = 0; r < 4; ++r) s[r] = bf2f(bv[nt][r]);
      s = MFMA16(aK0, aQ0, s);   // S^T: row=key, col=q; q pre-scaled 0.125*log2e
      s = MFMA16(aK1, aQ1, s);
      S[nt] = s;
    }
#pragma unroll
    for (int nt = 0; nt < 4; ++nt) {
      bf16x4 pw;
#pragma unroll
      for (int r = 0; r < 4; ++r) {
        float p = exp2f(S[nt][r]);
        lacc += p;
        pw[r] = f2bf(p);
      }
      // P[q=l15][key]: 4 consecutive keys -> one b64 write
      *(bf16x4*)&Plds[buf][w][l15][nt * 16 + quad * 4] = pw;
    }
    bf16x8 aP0 = *(const bf16x8*)&Plds[buf][w][l15][quad * 8];
    bf16x8 aP1 = *(const bf16x8*)&Plds[buf][w][l15][32 + quad * 8];
#pragma unroll
    for (int dt = 0; dt < 4; ++dt) {
      const short* vp = vb + (size_t)(dt * 16 + l15) * 2048 + j0;
      bf16x8 bV0 = *(const bf16x8*)vp;
      bf16x8 bV1 = *(const bf16x8*)(vp + 32);
      O[dt] = MFMA16(aP0, bV0, O[dt]);
      O[dt] = MFMA16(aP1, bV1, O[dt]);
    }
  }
  // l: sum across the 4 quads holding the same q (=l15)
  lacc += __shfl_xor(lacc, 16);
  lacc += __shfl_xor(lacc, 32);

  // write unnormalized partials
  float* Ob = Opart + (((size_t)half * 32 + bh) * 2048 + q0) * 64;
#pragma unroll
  for (int dt = 0; dt < 4; ++dt)
#pragma unroll
    for (int r = 0; r < 4; ++r)
      Ob[(size_t)(quad * 4 + r) * 64 + dt * 16 + l15] = O[dt][r];
  if (quad == 0)
    lpart[((size_t)half * 32 + bh) * 2048 + q0 + l15] = lacc;
}

// combine: attnO[b*2048+q][h*64+d] = (O0+O1)/(l0+l1), bf16
__global__ __launch_bounds__(256) void attn_combine(const float* __restrict__ Opart,
                                                    const float* __restrict__ lpart,
                                                    short* __restrict__ attnO) {
  const int gid = blockIdx.x * 256 + threadIdx.x;   // 524288 total
  const int dgrp = gid & 7;                         // 8 floats each
  const int q = (gid >> 3) & 2047;
  const int bh = gid >> 14;                         // 0..31
  const size_t o0 = (((size_t)bh) * 2048 + q) * 64 + dgrp * 8;
  const size_t o1 = (((size_t)(32 + bh)) * 2048 + q) * 64 + dgrp * 8;
  f32x4 a0 = *(const f32x4*)(Opart + o0);
  f32x4 a1 = *(const f32x4*)(Opart + o0 + 4);
  f32x4 b0 = *(const f32x4*)(Opart + o1);
  f32x4 b1 = *(const f32x4*)(Opart + o1 + 4);
  const float inv = 1.f / (lpart[(size_t)bh * 2048 + q] +
                           lpart[(size_t)(32 + bh) * 2048 + q]);
  bf16x8 o;
#pragma unroll
  for (int i = 0; i < 4; ++i) o[i] = f2bf((a0[i] + b0[i]) * inv);
#pragma unroll
  for (int i = 0; i < 4; ++i) o[4 + i] = f2bf((a1[i] + b1[i]) * inv);
  const int b = bh >> 3, h = bh & 7;
  *(bf16x8*)(attnO + ((size_t)(b * 2048 + q)) * 512 + h * 64 + dgrp * 8) = o;
}

// ---------------- K3: output projection (fp32 out) ----------------

__global__ __launch_bounds__(256) void gemm_out(const short* __restrict__ A,
                                                const short* __restrict__ BT,
                                                float* __restrict__ out) {
  __shared__ short As[128][40];
  __shared__ short Bs[128][40];
  const int t = threadIdx.x;
  const int w = t >> 6, lane = t & 63, l15 = lane & 15, quad = lane >> 4;
  const int wm = (w & 1) * 64, wn = (w >> 1) * 64;
  const int m0 = blockIdx.y * 128, n0 = blockIdx.x * 128;
  f32x4 acc[4][4];
#pragma unroll
  for (int i = 0; i < 4; ++i)
#pragma unroll
    for (int j = 0; j < 4; ++j) acc[i][j] = (f32x4){0.f, 0.f, 0.f, 0.f};

  gemm128_mainloop(A, BT, m0, n0, As, Bs, acc);

#pragma unroll
  for (int i = 0; i < 4; ++i)
#pragma unroll
    for (int j = 0; j < 4; ++j)
#pragma unroll
      for (int r = 0; r < 4; ++r)
        out[(size_t)(m0 + wm + i * 16 + quad * 4 + r) * 512 + n0 + wn + j * 16 + l15] =
            acc[i][j][r];
}

// ---------------- launch ----------------

extern "C" void kernel_launch(void* const* d_in, const int* in_sizes, int n_in,
                              void* d_out, int out_size, void* d_ws, size_t ws_size,
                              hipStream_t stream) {
  (void)in_sizes; (void)n_in; (void)out_size; (void)ws_size;
  const float* x        = (const float*)d_in[0];
  const float* pos_bias = (const float*)d_in[1];
  const float* w_qkv    = (const float*)d_in[2];
  const float* w_out    = (const float*)d_in[3];
  float* out = (float*)d_out;

  short* ws = (short*)d_ws;
  const size_t SEG = (size_t)32 * 2048 * 64;   // 4.19M elems
  short* q_ws  = ws;
  short* k_ws  = q_ws + SEG;
  short* v_t   = k_ws + SEG;
  short* attnO = v_t + SEG;
  short* xbf   = attnO + SEG;                  // [8192][512]
  short* wqkvT = xbf + SEG;                    // [1536][512]
  short* woutT = wqkvT + (size_t)1536 * 512;   // [512][512]
  short* biasT = woutT + (size_t)512 * 512;    // [8][2048][2048] bf16 (xL2E)
  float* Opart = (float*)(biasT + (size_t)8 * 2048 * 2048);  // [2][32][2048][64] fp32
  float* lpart = Opart + (size_t)2 * 32 * 2048 * 64;         // [2][32][2048] fp32

  cvt_bf16<<<2048, 256, 0, stream>>>(x, xbf);
  transpose_cvt<<<dim3(24, 8), 256, 0, stream>>>(w_qkv, wqkvT, 512, 1536);
  transpose_cvt<<<dim3(8, 8), 256, 0, stream>>>(w_out, woutT, 512, 512);
  bias_cvt<<<16384, 256, 0, stream>>>(pos_bias, biasT);
  gemm_qkv<<<dim3(12, 64), 256, 0, stream>>>(xbf, wqkvT, q_ws, k_ws, v_t);
  attn_kernel<<<2048, 256, 0, stream>>>(q_ws, k_ws, v_t, biasT, Opart, lpart);
  attn_combine<<<2048, 256, 0, stream>>>(Opart, lpart, attnO);
  gemm_out<<<dim3(4, 64), 256, 0, stream>>>(attnO, woutT, out);
}

// Round 7
// 569.755 us; speedup vs baseline: 1.0122x; 1.0122x over previous
//
#include <hip/hip_runtime.h>

typedef short bf16x8 __attribute__((ext_vector_type(8)));
typedef short bf16x4 __attribute__((ext_vector_type(4)));
typedef float f32x4 __attribute__((ext_vector_type(4)));

#define MFMA16(a, b, c) __builtin_amdgcn_mfma_f32_16x16x32_bf16(a, b, c, 0, 0, 0)

__device__ __forceinline__ short f2bf(float f) {
  unsigned u = __builtin_bit_cast(unsigned, f);
  u += 0x7fffu + ((u >> 16) & 1u);   // round-to-nearest-even
  return (short)(u >> 16);
}
__device__ __forceinline__ float bf2f(short s) {
  return __builtin_bit_cast(float, ((unsigned)(unsigned short)s) << 16);
}

// Problem sizes (fixed)
// B=4, N=2048, D=512, H=8, DH=64, M = B*N = 8192, 3*H*DH = 1536
#define L2E 1.44269504088896f

// ---------------- prep kernels ----------------

__global__ __launch_bounds__(256) void cvt_bf16(const float* __restrict__ in,
                                                short* __restrict__ out) {
  size_t i = ((size_t)blockIdx.x * 256 + threadIdx.x) * 8;
  const float4* p = (const float4*)(in + i);
  float4 a = p[0], b = p[1];
  bf16x8 v;
  v[0] = f2bf(a.x); v[1] = f2bf(a.y); v[2] = f2bf(a.z); v[3] = f2bf(a.w);
  v[4] = f2bf(b.x); v[5] = f2bf(b.y); v[6] = f2bf(b.z); v[7] = f2bf(b.w);
  *(bf16x8*)(out + i) = v;
}

// in: fp32 [K][N] -> out: bf16 [N][K]
__global__ __launch_bounds__(256) void transpose_cvt(const float* __restrict__ in,
                                                     short* __restrict__ out,
                                                     int K, int N) {
  __shared__ short Ts[64][72];
  const int t = threadIdx.x;
  const int k0 = blockIdx.y * 64, n1 = blockIdx.x * 64;
  const int kk = t >> 2, nq = (t & 3) * 16;
  const float* src = in + (size_t)(k0 + kk) * N + n1 + nq;
  float4 f0 = ((const float4*)src)[0], f1 = ((const float4*)src)[1];
  float4 f2 = ((const float4*)src)[2], f3 = ((const float4*)src)[3];
  Ts[nq + 0][kk] = f2bf(f0.x);  Ts[nq + 1][kk] = f2bf(f0.y);
  Ts[nq + 2][kk] = f2bf(f0.z);  Ts[nq + 3][kk] = f2bf(f0.w);
  Ts[nq + 4][kk] = f2bf(f1.x);  Ts[nq + 5][kk] = f2bf(f1.y);
  Ts[nq + 6][kk] = f2bf(f1.z);  Ts[nq + 7][kk] = f2bf(f1.w);
  Ts[nq + 8][kk] = f2bf(f2.x);  Ts[nq + 9][kk] = f2bf(f2.y);
  Ts[nq +10][kk] = f2bf(f2.z);  Ts[nq +11][kk] = f2bf(f2.w);
  Ts[nq +12][kk] = f2bf(f3.x);  Ts[nq +13][kk] = f2bf(f3.y);
  Ts[nq +14][kk] = f2bf(f3.z);  Ts[nq +15][kk] = f2bf(f3.w);
  __syncthreads();
  const int n = t >> 2, kq = (t & 3) * 16;
  short* dst = out + (size_t)(n1 + n) * K + k0 + kq;
  *(bf16x8*)dst = *(const bf16x8*)&Ts[n][kq];
  *(bf16x8*)(dst + 8) = *(const bf16x8*)&Ts[n][kq + 8];
}

// bias fp32 [8][2048][2048] -> biasP bf16 (x L2E), MFMA-C-fragment order:
// biasP[((hq16)*2048 + key)*16 + qdr], hq16 = h*128 + (qrow/16), qdr = qrow%16
// (proven layout from R5's 259us kernel; loads now explicitly vectorized)
__global__ __launch_bounds__(256) void bias_pack(const float* __restrict__ bias,
                                                 short* __restrict__ biasP) {
  __shared__ short T[16][272];
  const int t = threadIdx.x;
  const int hq = blockIdx.x;             // 0..1023 = h*128 + q16
  const int c0 = blockIdx.y * 256;
  const int rr = t >> 4, cc = (t & 15) * 16;
  const float* src = bias + ((size_t)(hq * 16 + rr)) * 2048 + c0 + cc;
  float4 f0 = ((const float4*)src)[0], f1 = ((const float4*)src)[1];
  float4 f2 = ((const float4*)src)[2], f3 = ((const float4*)src)[3];
  bf16x8 v0, v1;
  v0[0] = f2bf(f0.x * L2E); v0[1] = f2bf(f0.y * L2E);
  v0[2] = f2bf(f0.z * L2E); v0[3] = f2bf(f0.w * L2E);
  v0[4] = f2bf(f1.x * L2E); v0[5] = f2bf(f1.y * L2E);
  v0[6] = f2bf(f1.z * L2E); v0[7] = f2bf(f1.w * L2E);
  v1[0] = f2bf(f2.x * L2E); v1[1] = f2bf(f2.y * L2E);
  v1[2] = f2bf(f2.z * L2E); v1[3] = f2bf(f2.w * L2E);
  v1[4] = f2bf(f3.x * L2E); v1[5] = f2bf(f3.y * L2E);
  v1[6] = f2bf(f3.z * L2E); v1[7] = f2bf(f3.w * L2E);
  *(bf16x8*)&T[rr][cc] = v0;
  *(bf16x8*)&T[rr][cc + 8] = v1;
  __syncthreads();
  short* dst = biasP + ((size_t)hq * 2048 + c0 + t) * 16;
  bf16x8 o0, o1;
#pragma unroll
  for (int e = 0; e < 8; ++e) o0[e] = T[e][t];
#pragma unroll
  for (int e = 0; e < 8; ++e) o1[e] = T[8 + e][t];
  *(bf16x8*)dst = o0;
  *(bf16x8*)(dst + 8) = o1;
}

__global__ __launch_bounds__(256) void zero_l(float* __restrict__ l) {
  int i = blockIdx.x * 256 + threadIdx.x;
  *(f32x4*)(l + (size_t)i * 4) = (f32x4){0.f, 0.f, 0.f, 0.f};
}

// ---------------- shared GEMM mainloop: C[128x128] tile, K=512 ----------------

__device__ __forceinline__ void gemm128_mainloop(const short* __restrict__ A,
                                                 const short* __restrict__ BT,
                                                 int m0, int n0,
                                                 short (*As)[40], short (*Bs)[40],
                                                 f32x4 acc[4][4]) {
  const int t = threadIdx.x;
  const int w = t >> 6, lane = t & 63, l15 = lane & 15, quad = lane >> 4;
  const int wm = (w & 1) * 64, wn = (w >> 1) * 64;
  const int srow = t >> 1, skg = (t & 1) * 16;
  const short* aptr = A + (size_t)(m0 + srow) * 512 + skg;
  const short* bptr = BT + (size_t)(n0 + srow) * 512 + skg;
  for (int k0 = 0; k0 < 512; k0 += 32) {
    __syncthreads();
    *(bf16x8*)&As[srow][skg]     = *(const bf16x8*)(aptr + k0);
    *(bf16x8*)&As[srow][skg + 8] = *(const bf16x8*)(aptr + k0 + 8);
    *(bf16x8*)&Bs[srow][skg]     = *(const bf16x8*)(bptr + k0);
    *(bf16x8*)&Bs[srow][skg + 8] = *(const bf16x8*)(bptr + k0 + 8);
    __syncthreads();
    bf16x8 af[4], bfr[4];
#pragma unroll
    for (int i = 0; i < 4; ++i) af[i] = *(const bf16x8*)&As[wm + i * 16 + l15][quad * 8];
#pragma unroll
    for (int j = 0; j < 4; ++j) bfr[j] = *(const bf16x8*)&Bs[wn + j * 16 + l15][quad * 8];
#pragma unroll
    for (int i = 0; i < 4; ++i)
#pragma unroll
      for (int j = 0; j < 4; ++j)
        acc[i][j] = MFMA16(af[i], bfr[j], acc[i][j]);
  }
}

// ---------------- K1: QKV projection ----------------

__global__ __launch_bounds__(256) void gemm_qkv(const short* __restrict__ A,
                                                const short* __restrict__ BT,
                                                short* __restrict__ q_ws,
                                                short* __restrict__ k_ws,
                                                short* __restrict__ v_t) {
  __shared__ short As[128][40];
  __shared__ short Bs[128][40];
  __shared__ short Ts[64][136];
  const int t = threadIdx.x;
  const int w = t >> 6, lane = t & 63, l15 = lane & 15, quad = lane >> 4;
  const int wm = (w & 1) * 64, wn = (w >> 1) * 64;
  const int m0 = blockIdx.y * 128, n0 = blockIdx.x * 128;
  f32x4 acc[4][4];
#pragma unroll
  for (int i = 0; i < 4; ++i)
#pragma unroll
    for (int j = 0; j < 4; ++j) acc[i][j] = (f32x4){0.f, 0.f, 0.f, 0.f};

  gemm128_mainloop(A, BT, m0, n0, As, Bs, acc);

  const int which = n0 >> 9;            // 0=q 1=k 2=v
  const int b = m0 >> 11, seq0 = m0 & 2047;
  if (which < 2) {
    short* dst = (which == 0) ? q_ws : k_ws;
    const float scale = (which == 0) ? (0.125f * L2E) : 1.0f;
#pragma unroll
    for (int i = 0; i < 4; ++i)
#pragma unroll
      for (int j = 0; j < 4; ++j)
#pragma unroll
        for (int r = 0; r < 4; ++r) {
          int m_loc = wm + i * 16 + quad * 4 + r;
          int col = n0 + wn + j * 16 + l15;
          int h = (col >> 6) & 7, d = col & 63;
          dst[((size_t)(b * 8 + h) * 2048 + seq0 + m_loc) * 64 + d] =
              f2bf(acc[i][j][r] * scale);
        }
  } else {
    for (int half = 0; half < 2; ++half) {
      __syncthreads();
      if ((w >> 1) == half) {
#pragma unroll
        for (int i = 0; i < 4; ++i)
#pragma unroll
          for (int j = 0; j < 4; ++j)
#pragma unroll
            for (int r = 0; r < 4; ++r)
              Ts[j * 16 + l15][wm + i * 16 + quad * 4 + r] = f2bf(acc[i][j][r]);
      }
      __syncthreads();
      const int hd = ((n0 + half * 64) >> 6) & 7;
      const int dp = t >> 2, sq = (t & 3) * 32;
      short* dstp = v_t + ((size_t)(b * 8 + hd) * 64 + dp) * 2048 + seq0 + sq;
#pragma unroll
      for (int u = 0; u < 4; ++u)
        *(bf16x8*)(dstp + u * 8) = *(const bf16x8*)&Ts[dp][sq + u * 8];
    }
  }
}

// ---------------- K2a: score pass P = exp2(Q K^T + bias) ----------------
// GEMM-shaped, K=64 (one staging, 2 MFMA k-steps). 128x128 P tile per block.
// bias enters as accumulator init from the fragment-packed biasP. Row sums
// of P accumulate per-lane, 16-lane shuffle-reduce, one atomicAdd per row.

__global__ __launch_bounds__(256) void attn_score(const short* __restrict__ q_ws,
                                                  const short* __restrict__ k_ws,
                                                  const short* __restrict__ biasP,
                                                  short* __restrict__ P_ws,
                                                  float* __restrict__ l_ws) {
  __shared__ short Qs[128][72];
  __shared__ short Ks[128][72];
  const int t = threadIdx.x;
  const int w = t >> 6, lane = t & 63, l15 = lane & 15, quad = lane >> 4;
  const int wm = (w & 1) * 64, wn = (w >> 1) * 64;
  const int n0 = blockIdx.x * 128;   // key tile
  const int m0 = blockIdx.y * 128;   // q tile
  const int bh = blockIdx.z;
  const int h = bh & 7;

  {  // stage Q,K tiles (16KB each)
    const int row = t >> 1, col = (t & 1) * 32;
    const short* qp = q_ws + ((size_t)bh * 2048 + m0 + row) * 64 + col;
    const short* kp = k_ws + ((size_t)bh * 2048 + n0 + row) * 64 + col;
#pragma unroll
    for (int u = 0; u < 4; ++u) *(bf16x8*)&Qs[row][col + u * 8] = *(const bf16x8*)(qp + u * 8);
#pragma unroll
    for (int u = 0; u < 4; ++u) *(bf16x8*)&Ks[row][col + u * 8] = *(const bf16x8*)(kp + u * 8);
  }

  // bias -> accumulator init (coalesced 8B fragment loads, R5-proven pattern)
  f32x4 acc[4][4];
#pragma unroll
  for (int i = 0; i < 4; ++i) {
    const short* bi = biasP +
        ((size_t)(h * 128 + (m0 >> 4) + (wm >> 4) + i) * 2048) * 16 + quad * 4;
#pragma unroll
    for (int j = 0; j < 4; ++j) {
      bf16x4 bv = *(const bf16x4*)(bi + (size_t)(n0 + wn + j * 16 + l15) * 16);
      acc[i][j] = (f32x4){bf2f(bv[0]), bf2f(bv[1]), bf2f(bv[2]), bf2f(bv[3])};
    }
  }
  __syncthreads();

#pragma unroll
  for (int s = 0; s < 2; ++s) {
    bf16x8 af[4], bfr[4];
#pragma unroll
    for (int i = 0; i < 4; ++i) af[i] = *(const bf16x8*)&Qs[wm + i * 16 + l15][s * 32 + quad * 8];
#pragma unroll
    for (int j = 0; j < 4; ++j) bfr[j] = *(const bf16x8*)&Ks[wn + j * 16 + l15][s * 32 + quad * 8];
#pragma unroll
    for (int i = 0; i < 4; ++i)
#pragma unroll
      for (int j = 0; j < 4; ++j)
        acc[i][j] = MFMA16(af[i], bfr[j], acc[i][j]);
  }

  // exp2, store P (bf16), accumulate row partials
  float lpar[4][4];   // [i][r]
#pragma unroll
  for (int i = 0; i < 4; ++i)
#pragma unroll
    for (int r = 0; r < 4; ++r) lpar[i][r] = 0.f;
  short* Pb = P_ws + (size_t)bh * 2048 * 2048;
#pragma unroll
  for (int i = 0; i < 4; ++i)
#pragma unroll
    for (int j = 0; j < 4; ++j) {
      const int col = n0 + wn + j * 16 + l15;
#pragma unroll
      for (int r = 0; r < 4; ++r) {
        float p = exp2f(acc[i][j][r]);
        lpar[i][r] += p;
        const int row = m0 + wm + i * 16 + quad * 4 + r;
        Pb[(size_t)row * 2048 + col] = f2bf(p);
      }
    }
#pragma unroll
  for (int off = 1; off <= 8; off <<= 1)
#pragma unroll
    for (int i = 0; i < 4; ++i)
#pragma unroll
      for (int r = 0; r < 4; ++r) lpar[i][r] += __shfl_xor(lpar[i][r], off);
  if (l15 == 0) {
#pragma unroll
    for (int i = 0; i < 4; ++i)
#pragma unroll
      for (int r = 0; r < 4; ++r)
        atomicAdd(&l_ws[(size_t)bh * 2048 + m0 + wm + i * 16 + quad * 4 + r],
                  lpar[i][r]);
  }
}

// ---------------- K2b: O = (P V) / l ----------------
// Pure streaming MFMA loop: no exp2, no LDS, no bias. P loads register-
// double-buffered. One block = 64 q x 64 d, full 2048 keys, one (b,h).

__global__ __launch_bounds__(256) void attn_pv(const short* __restrict__ P_ws,
                                               const short* __restrict__ v_t,
                                               const float* __restrict__ l_ws,
                                               short* __restrict__ attnO) {
  const int t = threadIdx.x;
  const int w = t >> 6, lane = t & 63, l15 = lane & 15, quad = lane >> 4;
  const int bid = blockIdx.x;
  const int qb = bid & 31, bh = bid >> 5;
  const int b = bh >> 3, h = bh & 7;
  const int q0 = qb * 64 + w * 16;

  const short* Pb = P_ws + ((size_t)bh * 2048 + q0 + l15) * 2048 + quad * 8;
  const short* vb = v_t + (size_t)bh * 64 * 2048 + quad * 8;

  f32x4 O[4];
#pragma unroll
  for (int i = 0; i < 4; ++i) O[i] = (f32x4){0.f, 0.f, 0.f, 0.f};

  bf16x8 aP0[2], aP1[2];
  aP0[0] = *(const bf16x8*)(Pb);
  aP1[0] = *(const bf16x8*)(Pb + 32);

#pragma unroll 2
  for (int j0 = 0; j0 < 2048; j0 += 64) {
    const int cur = (j0 >> 6) & 1, nxt = cur ^ 1;
    const int jn = (j0 + 64) & 2047;        // wraps on last iter (harmless)
    aP0[nxt] = *(const bf16x8*)(Pb + jn);
    aP1[nxt] = *(const bf16x8*)(Pb + jn + 32);
#pragma unroll
    for (int dt = 0; dt < 4; ++dt) {
      const short* vp = vb + (size_t)(dt * 16 + l15) * 2048 + j0;
      bf16x8 bV0 = *(const bf16x8*)vp;
      bf16x8 bV1 = *(const bf16x8*)(vp + 32);
      O[dt] = MFMA16(aP0[cur], bV0, O[dt]);
      O[dt] = MFMA16(aP1[cur], bV1, O[dt]);
    }
  }

  float linv[4];
  const float* lb = l_ws + (size_t)bh * 2048 + q0 + quad * 4;
#pragma unroll
  for (int r = 0; r < 4; ++r) linv[r] = 1.f / lb[r];
#pragma unroll
  for (int dt = 0; dt < 4; ++dt)
#pragma unroll
    for (int r = 0; r < 4; ++r)
      attnO[((size_t)(b * 2048 + q0 + quad * 4 + r)) * 512 + h * 64 + dt * 16 + l15] =
          f2bf(O[dt][r] * linv[r]);
}

// ---------------- K3: output projection (fp32 out) ----------------

__global__ __launch_bounds__(256) void gemm_out(const short* __restrict__ A,
                                                const short* __restrict__ BT,
                                                float* __restrict__ out) {
  __shared__ short As[128][40];
  __shared__ short Bs[128][40];
  const int t = threadIdx.x;
  const int w = t >> 6, lane = t & 63, l15 = lane & 15, quad = lane >> 4;
  const int wm = (w & 1) * 64, wn = (w >> 1) * 64;
  const int m0 = blockIdx.y * 128, n0 = blockIdx.x * 128;
  f32x4 acc[4][4];
#pragma unroll
  for (int i = 0; i < 4; ++i)
#pragma unroll
    for (int j = 0; j < 4; ++j) acc[i][j] = (f32x4){0.f, 0.f, 0.f, 0.f};

  gemm128_mainloop(A, BT, m0, n0, As, Bs, acc);

#pragma unroll
  for (int i = 0; i < 4; ++i)
#pragma unroll
    for (int j = 0; j < 4; ++j)
#pragma unroll
      for (int r = 0; r < 4; ++r)
        out[(size_t)(m0 + wm + i * 16 + quad * 4 + r) * 512 + n0 + wn + j * 16 + l15] =
            acc[i][j][r];
}

// ---------------- launch ----------------

extern "C" void kernel_launch(void* const* d_in, const int* in_sizes, int n_in,
                              void* d_out, int out_size, void* d_ws, size_t ws_size,
                              hipStream_t stream) {
  (void)in_sizes; (void)n_in; (void)out_size; (void)ws_size;
  const float* x        = (const float*)d_in[0];
  const float* pos_bias = (const float*)d_in[1];
  const float* w_qkv    = (const float*)d_in[2];
  const float* w_out    = (const float*)d_in[3];
  float* out = (float*)d_out;

  short* ws = (short*)d_ws;
  const size_t SEG = (size_t)32 * 2048 * 64;   // 4.19M elems
  short* q_ws  = ws;
  short* k_ws  = q_ws + SEG;
  short* v_t   = k_ws + SEG;
  short* attnO = v_t + SEG;
  short* xbf   = attnO + SEG;                  // [8192][512]
  short* wqkvT = xbf + SEG;                    // [1536][512]
  short* woutT = wqkvT + (size_t)1536 * 512;   // [512][512]
  short* biasP = woutT + (size_t)512 * 512;    // [1024][2048][16] bf16 (xL2E)
  short* P_ws  = biasP + (size_t)1024 * 2048 * 16;   // [32][2048][2048] bf16
  float* l_ws  = (float*)(P_ws + (size_t)32 * 2048 * 2048);  // [32][2048] fp32

  cvt_bf16<<<2048, 256, 0, stream>>>(x, xbf);
  transpose_cvt<<<dim3(24, 8), 256, 0, stream>>>(w_qkv, wqkvT, 512, 1536);
  transpose_cvt<<<dim3(8, 8), 256, 0, stream>>>(w_out, woutT, 512, 512);
  bias_pack<<<dim3(1024, 8), 256, 0, stream>>>(pos_bias, biasP);
  zero_l<<<64, 256, 0, stream>>>(l_ws);
  gemm_qkv<<<dim3(12, 64), 256, 0, stream>>>(xbf, wqkvT, q_ws, k_ws, v_t);
  attn_score<<<dim3(16, 16, 32), 256, 0, stream>>>(q_ws, k_ws, biasP, P_ws, l_ws);
  attn_pv<<<1024, 256, 0, stream>>>(P_ws, v_t, l_ws, attnO);
  gemm_out<<<dim3(4, 64), 256, 0, stream>>>(attnO, woutT, out);
}